// Round 2
// baseline (26796.545 us; speedup 1.0000x reference)
//
#include <hip/hip_runtime.h>

typedef __bf16 bf16;
typedef __bf16 bf16x8 __attribute__((ext_vector_type(8)));
typedef float  f32x4  __attribute__((ext_vector_type(4)));

#define B_TOT 4096
#define T_SEQ 64
#define F_IN  32
#define C_CTY 64
#define L_LAT 256
#define W_HID 512
#define NT_OUT 8
#define SUBSTEPS 10
#define MB   16     // batch rows per block
#define NBLK 256    // one block per CU
#define NTHR 512    // 8 waves
#define YS   260    // fp32 Y row stride (1040 B = 65*16 -> odd 16B slots)

// Tsit5 tableau
constexpr float A21 = 0.161f;
constexpr float A31 = -0.008480655492356989f, A32 = 0.335480655492357f;
constexpr float A41 = 2.8971530571054935f, A42 = -6.359448489975075f, A43 = 4.362295432869581f;
constexpr float A51 = 5.325864828439257f, A52 = -11.748883564062828f, A53 = 7.4955393428898365f, A54 = -0.09249506636175525f;
constexpr float A61 = 5.86145544294642f, A62 = -12.92096931784711f, A63 = 8.159367898576159f, A64 = -0.071584973281401f, A65 = -0.028269050394068383f;
constexpr float BC1 = 0.09646076681806523f, BC2 = 0.01f, BC3 = 0.4798896504144996f;
constexpr float BC4 = 1.379008574103742f, BC5 = -3.290069515436081f, BC6 = 2.324710524099774f;
constexpr float DT = 0.1f;
constexpr float BROW[5][5] = {
    {A21, 0, 0, 0, 0},
    {A31, A32, 0, 0, 0},
    {A41, A42, A43, 0, 0},
    {A51, A52, A53, A54, 0},
    {A61, A62, A63, A64, A65}};
constexpr float FCF[6] = {BC1, BC2, BC3, BC4, BC5, BC6};

__device__ __forceinline__ f32x4 MFMA(bf16x8 a, bf16x8 b, f32x4 c) {
    return __builtin_amdgcn_mfma_f32_16x16x32_bf16(a, b, c, 0, 0, 0);
}
__device__ __forceinline__ float eluf(float x) { return x > 0.f ? x : __expf(x) - 1.f; }
__device__ __forceinline__ float sigm_f(float x) { return 1.f / (1.f + __expf(-x)); }
__device__ __forceinline__ float tanh_f(float x) { return 1.f - 2.f / (__expf(2.f * x) + 1.f); }

// position (bf16 index) of element (feature n, batch row b) in A-frag-linear layout:
// frag kk = n>>5 (k-block of 32), lane = b | (((n>>3)&3)<<4), elem j = n&7
__device__ __forceinline__ int fragpos(int n, int b) {
    return (((n >> 5) * 64) + (b | (((n >> 3) & 3) << 4))) * 8 + (n & 7);
}

// GEMM phase: acc[nt] += Act @ Wp^T slice. Act in frag-linear LDS (KK frags),
// Wp packed in fragment order (frag f = (w*NT+nt)*KK+kk, 512 bf16/frag, lane*8 within).
template<int NT, int KK>
__device__ __forceinline__ void mfma_block(const bf16* __restrict__ Wp,
                                           const bf16* __restrict__ act,
                                           int w, int lane, f32x4* acc) {
    const bf16* base = Wp + ((size_t)w * NT) * KK * 512 + lane * 8;
    bf16x8 bb[2][NT];
    #pragma unroll
    for (int nt = 0; nt < NT; ++nt)
        bb[0][nt] = *(const bf16x8*)(base + (size_t)nt * KK * 512);
    bf16x8 a[KK];
    #pragma unroll
    for (int kk = 0; kk < KK; ++kk)
        a[kk] = *(const bf16x8*)(act + (kk * 64 + lane) * 8);
    #pragma unroll
    for (int kk = 0; kk < KK; ++kk) {
        const int cur = kk & 1;
        if (kk + 1 < KK) {
            #pragma unroll
            for (int nt = 0; nt < NT; ++nt)
                bb[cur ^ 1][nt] = *(const bf16x8*)(base + ((size_t)nt * KK + kk + 1) * 512);
        }
        #pragma unroll
        for (int nt = 0; nt < NT; ++nt)
            acc[nt] = MFMA(a[kk], bb[cur][nt], acc[nt]);
    }
}

// One Tsit5 stage: y_stage in P (frags 0..7) -> k_{STAGE+1}; build next y_stage -> Q frags 0..7.
// Wave-local build: wave w owns features [32w, 32w+32) of all k's and y_stage.
// 3 barriers per stage.
template<int STAGE>
__device__ void mlp_stage(bf16* __restrict__ P, bf16* __restrict__ Q,
                          bf16* const* kp, float* __restrict__ sY_,
                          const bf16* __restrict__ W0p, const bf16* __restrict__ W1p,
                          const bf16* __restrict__ W2p,
                          const float* rb, int w, int lane) {
    const int lm = lane & 15, q4 = (lane >> 4) << 2;

    // ---- L0: h1 = elu(y_stage @ W0^T + b0), read P frags 0..7, write Q (16 frags) ----
    {
        f32x4 acc[4];
        #pragma unroll
        for (int nt = 0; nt < 4; ++nt) acc[nt] = {0.f, 0.f, 0.f, 0.f};
        mfma_block<4, 8>(W0p, P, w, lane, acc);
        #pragma unroll
        for (int nt = 0; nt < 4; ++nt) {
            #pragma unroll
            for (int r = 0; r < 4; ++r)
                Q[fragpos(w * 64 + nt * 16 + lm, q4 + r)] = (bf16)eluf(acc[nt][r] + rb[nt]);
        }
    }
    __syncthreads();

    // ---- L1: h2 = elu(h1 @ W1^T + b1), read Q, write P ----
    {
        f32x4 acc[4];
        #pragma unroll
        for (int nt = 0; nt < 4; ++nt) acc[nt] = {0.f, 0.f, 0.f, 0.f};
        mfma_block<4, 16>(W1p, Q, w, lane, acc);
        #pragma unroll
        for (int nt = 0; nt < 4; ++nt) {
            #pragma unroll
            for (int r = 0; r < 4; ++r)
                P[fragpos(w * 64 + nt * 16 + lm, q4 + r)] = (bf16)eluf(acc[nt][r] + rb[4 + nt]);
        }
    }
    __syncthreads();

    // ---- L2: k = h2 @ W2^T + b2 (read P), then wave-local build -> Q frags 0..7 ----
    {
        f32x4 acc[2];
        acc[0] = {0.f, 0.f, 0.f, 0.f};
        acc[1] = {0.f, 0.f, 0.f, 0.f};
        mfma_block<2, 16>(W2p, P, w, lane, acc);
        bf16* kdst = kp[STAGE];
        #pragma unroll
        for (int nt = 0; nt < 2; ++nt) {
            #pragma unroll
            for (int r = 0; r < 4; ++r)
                kdst[fragpos(w * 32 + nt * 16 + lm, q4 + r)] = (bf16)(acc[nt][r] + rb[8 + nt]);
        }
        // build (same wave wrote all of features [32w,32w+32) -> lgkmcnt ordering suffices)
        const int b = lane & 15, q = lane >> 4;
        float* yb = &sY_[b * YS + 32 * w + 8 * q];
        f32x4 y0 = *(const f32x4*)yb;
        f32x4 y1 = *(const f32x4*)(yb + 4);
        float y[8] = {y0[0], y0[1], y0[2], y0[3], y1[0], y1[1], y1[2], y1[3]};
        if constexpr (STAGE < 5) {
            #pragma unroll
            for (int i = 0; i <= STAGE; ++i) {
                bf16x8 kv = *(const bf16x8*)&kp[i][(w * 64 + lane) * 8];
                const float c = DT * BROW[STAGE][i];
                #pragma unroll
                for (int j = 0; j < 8; ++j) y[j] += c * (float)kv[j];
            }
        } else {
            #pragma unroll
            for (int i = 0; i < 6; ++i) {
                bf16x8 kv = *(const bf16x8*)&kp[i][(w * 64 + lane) * 8];
                const float c = DT * FCF[i];
                #pragma unroll
                for (int j = 0; j < 8; ++j) y[j] += c * (float)kv[j];
            }
            // commit y_{n+1}
            *(f32x4*)yb = {y[0], y[1], y[2], y[3]};
            *(f32x4*)(yb + 4) = {y[4], y[5], y[6], y[7]};
        }
        bf16x8 o;
        #pragma unroll
        for (int j = 0; j < 8; ++j) o[j] = (bf16)y[j];
        *(bf16x8*)&Q[(w * 64 + lane) * 8] = o;
    }
    __syncthreads();
}

__global__ void __launch_bounds__(NTHR, 2)
k_main(const float* __restrict__ x_seq, const int* __restrict__ cidx,
       const float* __restrict__ b_n, const float* __restrict__ b0,
       const float* __restrict__ b1, const float* __restrict__ b2,
       const float* __restrict__ W_dec, const float* __restrict__ b_dec,
       const bf16* __restrict__ WihP, const bf16* __restrict__ WhhP,
       const bf16* __restrict__ W0p, const bf16* __restrict__ W1p,
       const bf16* __restrict__ W2p, const float* __restrict__ bias_c,
       float* __restrict__ out, int H) {
    __shared__ __align__(16) bf16 sA[16 * 512];
    __shared__ __align__(16) bf16 sB[16 * 512];
    __shared__ __align__(16) bf16 sK0[8 * 512];
    __shared__ __align__(16) bf16 sK1[8 * 512];
    __shared__ __align__(16) bf16 sK2[8 * 512];
    __shared__ __align__(16) bf16 sK3[8 * 512];
    __shared__ __align__(16) bf16 sK4[8 * 512];
    __shared__ __align__(16) float sY[MB * YS];
    __shared__ __align__(16) bf16 sHX[9 * 512];        // GRU [h | x] frags
    __shared__ __align__(16) bf16 sSg[16 * 520];       // GRU r/z sums; ODE: k6 scratch
    __shared__ __align__(16) bf16 sInn[16 * 264];
    __shared__ __align__(16) bf16 sHn[16 * 264];
    __shared__ float sWdec[NT_OUT * L_LAT];
    __shared__ float sBdec[NT_OUT];
    __shared__ int   sCty[MB];

    const int tid = threadIdx.x, w = tid >> 6, lane = tid & 63;
    const int lm = lane & 15, q4 = (lane >> 4) << 2;
    const int b0row = blockIdx.x * MB;

    bf16* kp[6] = {sK0, sK1, sK2, sK3, sK4, sSg};

    for (int i = tid; i < NT_OUT * L_LAT; i += NTHR) sWdec[i] = W_dec[i];
    if (tid < NT_OUT) sBdec[tid] = b_dec[tid];
    if (tid < MB) sCty[tid] = cidx[b0row + tid];
    for (int i = tid; i < MB * YS; i += NTHR) sY[i] = 0.f;

    // per-wave bias preload (cols owned by this wave)
    float rb[10];
    #pragma unroll
    for (int nt = 0; nt < 4; ++nt) rb[nt] = b0[w * 64 + nt * 16 + lm];
    #pragma unroll
    for (int nt = 0; nt < 4; ++nt) rb[4 + nt] = b1[w * 64 + nt * 16 + lm];
    #pragma unroll
    for (int nt = 0; nt < 2; ++nt) rb[8 + nt] = b2[w * 32 + nt * 16 + lm];
    __syncthreads();

    // ================= GRU encoder =================
    for (int t = 0; t < T_SEQ; ++t) {
        // build hx frags: h (kk 0..7) from sY, x (kk 8) from global
        {
            const int kk = tid >> 6, L = tid & 63;
            const int b = L & 15, q = L >> 4;
            const float* yb = &sY[b * YS + kk * 32 + 8 * q];
            f32x4 h0 = *(const f32x4*)yb;
            f32x4 h1v = *(const f32x4*)(yb + 4);
            bf16x8 o;
            o[0] = (bf16)h0[0]; o[1] = (bf16)h0[1]; o[2] = (bf16)h0[2]; o[3] = (bf16)h0[3];
            o[4] = (bf16)h1v[0]; o[5] = (bf16)h1v[1]; o[6] = (bf16)h1v[2]; o[7] = (bf16)h1v[3];
            *(bf16x8*)&sHX[(kk * 64 + L) * 8] = o;
            if (tid < 64) {
                const float* xs = &x_seq[((size_t)(b0row + b) * T_SEQ + t) * F_IN + 8 * q];
                f32x4 x0 = *(const f32x4*)xs;
                f32x4 x1 = *(const f32x4*)(xs + 4);
                bf16x8 ox;
                ox[0] = (bf16)x0[0]; ox[1] = (bf16)x0[1]; ox[2] = (bf16)x0[2]; ox[3] = (bf16)x0[3];
                ox[4] = (bf16)x1[0]; ox[5] = (bf16)x1[1]; ox[6] = (bf16)x1[2]; ox[7] = (bf16)x1[3];
                *(bf16x8*)&sHX[(8 * 64 + L) * 8] = ox;
            }
        }
        __syncthreads();
        // MFMA: wave w -> cols (w*6+nt)*16+lm, nt 0..5
        {
            f32x4 aH[6], aX[6];
            #pragma unroll
            for (int nt = 0; nt < 6; ++nt) {
                aH[nt] = {0.f, 0.f, 0.f, 0.f};
                aX[nt] = {0.f, 0.f, 0.f, 0.f};
            }
            bf16x8 ax = *(const bf16x8*)&sHX[(8 * 64 + lane) * 8];
            #pragma unroll
            for (int nt = 0; nt < 6; ++nt) {
                bf16x8 bwx = *(const bf16x8*)&WihP[((size_t)(w * 6 + nt)) * 512 + lane * 8];
                aX[nt] = MFMA(ax, bwx, aX[nt]);
            }
            bf16x8 a[8];
            #pragma unroll
            for (int kk = 0; kk < 8; ++kk) a[kk] = *(const bf16x8*)&sHX[(kk * 64 + lane) * 8];
            #pragma unroll
            for (int kk = 0; kk < 8; ++kk) {
                #pragma unroll
                for (int nt = 0; nt < 6; ++nt) {
                    bf16x8 bwh = *(const bf16x8*)&WhhP[(((size_t)(w * 6 + nt)) * 8 + kk) * 512 + lane * 8];
                    aH[nt] = MFMA(a[kk], bwh, aH[nt]);
                }
            }
            #pragma unroll
            for (int nt = 0; nt < 6; ++nt) {
                const int c = w * 6 + nt, n = c * 16 + lm;
                if (c < 32) {
                    #pragma unroll
                    for (int r = 0; r < 4; ++r)
                        sSg[(q4 + r) * 520 + n] = (bf16)(aH[nt][r] + aX[nt][r]);
                } else {
                    #pragma unroll
                    for (int r = 0; r < 4; ++r) {
                        sInn[(q4 + r) * 264 + n - 512] = (bf16)aX[nt][r];
                        sHn[(q4 + r) * 264 + n - 512] = (bf16)aH[nt][r];
                    }
                }
            }
        }
        __syncthreads();
        // gates: tid -> (row, 8 feats)
        {
            const int row = tid >> 5, jb = (tid & 31) * 8;
            const float* bc = bias_c + (size_t)sCty[row] * 768;
            #pragma unroll
            for (int e = 0; e < 8; ++e) {
                const int j = jb + e;
                const float Sr = (float)sSg[row * 520 + j] + bc[j];
                const float Sz = (float)sSg[row * 520 + 256 + j] + bc[256 + j];
                const float inn = (float)sInn[row * 264 + j] + bc[512 + j];
                const float hn = (float)sHn[row * 264 + j];
                const float r = sigm_f(Sr), z = sigm_f(Sz);
                const float nn = tanh_f(inn + r * (hn + b_n[j]));
                const float h = sY[row * YS + j];
                sY[row * YS + j] = nn + z * (h - nn);
            }
        }
        __syncthreads();
    }

    // initial y_stage -> sA (wave-local feats)
    {
        const int b = lane & 15, q = lane >> 4;
        const float* yb = &sY[b * YS + 32 * w + 8 * q];
        f32x4 y0 = *(const f32x4*)yb;
        f32x4 y1 = *(const f32x4*)(yb + 4);
        bf16x8 o;
        o[0] = (bf16)y0[0]; o[1] = (bf16)y0[1]; o[2] = (bf16)y0[2]; o[3] = (bf16)y0[3];
        o[4] = (bf16)y1[0]; o[5] = (bf16)y1[1]; o[6] = (bf16)y1[2]; o[7] = (bf16)y1[3];
        *(bf16x8*)&sA[(w * 64 + lane) * 8] = o;
    }
    __syncthreads();

    // ================= Neural ODE (Tsit5) + decode =================
    for (int u = 0; u < H; ++u) {
        for (int s = 0; s < SUBSTEPS; ++s) {
            mlp_stage<0>(sA, sB, kp, sY, W0p, W1p, W2p, rb, w, lane);
            mlp_stage<1>(sB, sA, kp, sY, W0p, W1p, W2p, rb, w, lane);
            mlp_stage<2>(sA, sB, kp, sY, W0p, W1p, W2p, rb, w, lane);
            mlp_stage<3>(sB, sA, kp, sY, W0p, W1p, W2p, rb, w, lane);
            mlp_stage<4>(sA, sB, kp, sY, W0p, W1p, W2p, rb, w, lane);
            mlp_stage<5>(sB, sA, kp, sY, W0p, W1p, W2p, rb, w, lane);
        }
        // decode (sY stable until next stage-5; barrier at stage-5 exit covers writes)
        if (tid < MB * NT_OUT) {
            const int m = tid >> 3, tt = tid & 7;
            float acc = sBdec[tt];
            const float* wd = &sWdec[tt * L_LAT];
            #pragma unroll 4
            for (int l = 0; l < L_LAT; l += 4) {
                f32x4 yv = *(const f32x4*)&sY[m * YS + l];
                acc += yv[0] * wd[l] + yv[1] * wd[l + 1] + yv[2] * wd[l + 2] + yv[3] * wd[l + 3];
            }
            out[((size_t)(b0row + m) * H + u) * NT_OUT + tt] = acc;
        }
    }
}

// Pack fp32 weight [OUT][Ksrc] (use cols koff..koff+K) into MFMA-fragment order bf16:
// frag f = c*(K/32)+kk; within frag, lane's 8 elems = row c*16+(lane&15), k kk*32+(lane>>4)*8+j
__global__ void k_pack(const float* __restrict__ src, bf16* __restrict__ dst,
                       int OUT, int K, int Ksrc, int koff) {
    const int total = (OUT * K) >> 3;
    for (int g = blockIdx.x * blockDim.x + threadIdx.x; g < total; g += gridDim.x * blockDim.x) {
        const int lane = g & 63, f = g >> 6;
        const int KK = K >> 5;
        const int kk = f % KK, c = f / KK;
        const int col = c * 16 + (lane & 15);
        const int k0 = kk * 32 + ((lane >> 4) << 3);
        bf16x8 o;
        #pragma unroll
        for (int j = 0; j < 8; ++j) o[j] = (bf16)src[(size_t)col * Ksrc + koff + k0 + j];
        *(bf16x8*)&dst[(size_t)g * 8] = o;
    }
}

__global__ void k_bias(const float* __restrict__ W_ih, const float* __restrict__ b_ih,
                       float* __restrict__ bias_c) {
    const int i = blockIdx.x * blockDim.x + threadIdx.x;
    if (i < C_CTY * 3 * L_LAT) {
        const int c = i / (3 * L_LAT), n = i - c * (3 * L_LAT);
        bias_c[i] = W_ih[(size_t)n * (F_IN + C_CTY) + F_IN + c] + b_ih[n];
    }
}

extern "C" void kernel_launch(void* const* d_in, const int* in_sizes, int n_in,
                              void* d_out, int out_size, void* d_ws, size_t ws_size,
                              hipStream_t stream) {
    const float* x_seq = (const float*)d_in[0];
    const int*   cidx  = (const int*)d_in[1];
    const float* W_ih  = (const float*)d_in[3];
    const float* W_hh  = (const float*)d_in[4];
    const float* b_ih  = (const float*)d_in[5];
    const float* b_n   = (const float*)d_in[6];
    const float* W0    = (const float*)d_in[7];
    const float* b0    = (const float*)d_in[8];
    const float* W1    = (const float*)d_in[9];
    const float* b1    = (const float*)d_in[10];
    const float* W2    = (const float*)d_in[11];
    const float* b2    = (const float*)d_in[12];
    const float* W_dec = (const float*)d_in[13];
    const float* b_dec = (const float*)d_in[14];
    float* out = (float*)d_out;
    const int H = out_size / (B_TOT * NT_OUT);

    char* ws = (char*)d_ws;
    bf16*  W0p    = (bf16*)(ws + 0);         // 512*256 bf16 = 262144 B
    bf16*  W1p    = (bf16*)(ws + 262144);    // 512*512      = 524288 B
    bf16*  W2p    = (bf16*)(ws + 786432);    // 256*512      = 262144 B
    bf16*  WhhP   = (bf16*)(ws + 1048576);   // 768*256      = 393216 B
    bf16*  WihP   = (bf16*)(ws + 1441792);   // 768*32       = 49152 B
    float* bias_c = (float*)(ws + 1490944);  // 64*768 f32   = 196608 B

    k_pack<<<64, 256, 0, stream>>>(W0, W0p, 512, 256, 256, 0);
    k_pack<<<128, 256, 0, stream>>>(W1, W1p, 512, 512, 512, 0);
    k_pack<<<64, 256, 0, stream>>>(W2, W2p, 256, 512, 512, 0);
    k_pack<<<96, 256, 0, stream>>>(W_hh, WhhP, 768, 256, 256, 0);
    k_pack<<<12, 256, 0, stream>>>(W_ih, WihP, 768, 32, 96, 0);
    k_bias<<<(C_CTY * 3 * L_LAT + 255) / 256, 256, 0, stream>>>(W_ih, b_ih, bias_c);

    k_main<<<NBLK, NTHR, 0, stream>>>(x_seq, cidx, b_n, b0, b1, b2, W_dec, b_dec,
                                      WihP, WhhP, W0p, W1p, W2p, bias_c, out, H);
}